// Round 5
// baseline (127.926 us; speedup 1.0000x reference)
//
#include <hip/hip_runtime.h>
#include <math.h>

// Fuzzy LeNet-5, Yager p=1 == Lukasiewicz: T(a,b)=max(0,a+b-1).
// Fuzzy conv == max-plus conv: out = relu(max_{c,kh,kw}(x+w) - 1).
// maxpool2 folds into the conv via dilated 6x6 weights:
//   W'[uy][ux] = max_{dy,dx in {0,1}, uy-dy,ux-dx in [0,5)} w[uy-dy][ux-dx]
//
// R4 post-mortem: 3-kernel marginal cost ~36 us vs 1-kernel fixed overhead
// 58.3 us => graph node-to-node launch overhead dominates (~7-10 us/node).
// This round: SINGLE launch, 768 blocks (img,oc). Producer blocks write conv1
// slices + release a per-(img,oc) magic flag; the 128 oc==0 blocks acquire-spin
// (overlapped with w2 dilation) then run conv2+head in-block. launch_bounds
// (256,3) guarantees 3 blocks/CU => all 768 co-resident => no deadlock.
// Flags need no init: any poison value != MAGIC, producers atomicExch MAGIC.

#define MAGIC 0x5A17C0DEu

__global__ __launch_bounds__(256, 3) void fused_lenet(
    const float* __restrict__ x,   // [B,3,32,32]
    const float* __restrict__ w1,  // [6,3,5,5]
    const float* __restrict__ w2,  // [16,6,5,5]
    const float* __restrict__ w3,  // [120,16,5,5]
    const float* __restrict__ wd,  // [120,84]
    const float* __restrict__ wf,  // [84,10]
    const float* __restrict__ bfv, // [10]
    float* __restrict__ a1,        // ws: [B,6,14,14]
    unsigned* __restrict__ flags,  // ws: [B,6]
    float* __restrict__ out)       // [B,10]
{
    const int bx = blockIdx.x;
    const int img = bx / 6;
    const int oc = bx - img * 6;
    const int tid = threadIdx.x;

    __shared__ float s_w1d[108];            // dilated w1 slice [c][uy][ux(6)]
    __shared__ float s_w2d[16 * 216];       // dilated w2 [oc][c][uy][ux(6)]
    __shared__ __align__(16) float s_a2[400];
    __shared__ float s_a3[120];
    __shared__ float s_a4[84];
    __shared__ float s_logits[10];
    __shared__ float s_red[2];

    // ---- Phase 1a: dilate this block's w1 slice
    if (tid < 108) {
        const int c = tid / 36, v = tid - c * 36;
        const int r = v / 6, col = v - r * 6;
        const float* wb = w1 + oc * 75 + c * 25;
        float m = -1e30f;
        #pragma unroll
        for (int dy = 0; dy < 2; ++dy) {
            const int kh = r - dy;
            if ((unsigned)kh > 4u) continue;
            #pragma unroll
            for (int dx = 0; dx < 2; ++dx) {
                const int kw = col - dx;
                if ((unsigned)kw > 4u) continue;
                m = fmaxf(m, wb[kh * 5 + kw]);
            }
        }
        s_w1d[tid] = m;
    }
    __syncthreads();

    // ---- Phase 1b: conv1 [3,32,32] -> [14,14] for this (img,oc)
    if (tid < 196) {
        const int py = tid / 14, px = tid - py * 14;
        const float* xb = x + img * 3072 + 2 * py * 32 + 2 * px;
        float m = -1e30f;
        for (int c = 0; c < 3; ++c) {
            const float* xc = xb + c * 1024;
            const float* wc = s_w1d + c * 36;
            #pragma unroll
            for (int uy = 0; uy < 6; ++uy) {
                const float2 x0 = *(const float2*)(xc + uy * 32);
                const float2 x1 = *(const float2*)(xc + uy * 32 + 2);
                const float2 x2 = *(const float2*)(xc + uy * 32 + 4);
                const float2 w0 = *(const float2*)(wc + uy * 6);
                const float2 w1v = *(const float2*)(wc + uy * 6 + 2);
                const float2 w2v = *(const float2*)(wc + uy * 6 + 4);
                m = fmaxf(m, fmaxf(fmaxf(x0.x + w0.x, x0.y + w0.y),
                          fmaxf(fmaxf(x1.x + w1v.x, x1.y + w1v.y),
                                fmaxf(x2.x + w2v.x, x2.y + w2v.y))));
            }
        }
        a1[img * 1176 + oc * 196 + tid] = fmaxf(m - 1.0f, 0.0f);
    }
    __syncthreads();
    if (tid == 0)
        __hip_atomic_exchange(&flags[img * 6 + oc], MAGIC,
                              __ATOMIC_RELEASE, __HIP_MEMORY_SCOPE_AGENT);
    if (oc != 0) return;   // producers done; consumers (oc==0) continue

    // ---- Consumer: dilate w2 while producers finish
    for (int e = tid; e < 3456; e += 256) {
        const int o2 = e / 216, u = e - o2 * 216;
        const int c = u / 36, v = u - c * 36;
        const int r = v / 6, col = v - r * 6;
        const float* wb = w2 + o2 * 150 + c * 25;
        float m = -1e30f;
        #pragma unroll
        for (int dy = 0; dy < 2; ++dy) {
            const int kh = r - dy;
            if ((unsigned)kh > 4u) continue;
            #pragma unroll
            for (int dx = 0; dx < 2; ++dx) {
                const int kw = col - dx;
                if ((unsigned)kw > 4u) continue;
                m = fmaxf(m, wb[kh * 5 + kw]);
            }
        }
        s_w2d[e] = m;
    }

    // ---- Wait for this image's 6 conv1 slices
    if (tid < 6) {
        int guard = 0;
        while (__hip_atomic_load(&flags[img * 6 + tid],
                                 __ATOMIC_ACQUIRE, __HIP_MEMORY_SCOPE_AGENT)
               != MAGIC) {
            __builtin_amdgcn_s_sleep(2);
            if (++guard > (1 << 27)) break;   // safety: never hang the bench
        }
    }
    __syncthreads();
    __threadfence();   // L1 invalidate so a1 reads see producer writes

    // ---- conv2 [6,14,14] -> [16,5,5]; 200 threads, 2 oc each, shared x loads
    if (tid < 200) {
        const int ocl = tid / 25;            // 0..7
        const int pix = tid - ocl * 25;
        const int py = pix / 5, px = pix - py * 5;
        const float* xb = a1 + img * 1176 + 2 * py * 14 + 2 * px;
        const float* wA = s_w2d + ocl * 216;
        const float* wB = s_w2d + (ocl + 8) * 216;
        float mA = -1e30f, mB = -1e30f;
        for (int c = 0; c < 6; ++c) {
            const float* xc = xb + c * 196;
            const float* wcA = wA + c * 36;
            const float* wcB = wB + c * 36;
            #pragma unroll
            for (int uy = 0; uy < 6; ++uy) {
                const float2 x0 = *(const float2*)(xc + uy * 14);
                const float2 x1 = *(const float2*)(xc + uy * 14 + 2);
                const float2 x2 = *(const float2*)(xc + uy * 14 + 4);
                const float2 a0 = *(const float2*)(wcA + uy * 6);
                const float2 a1v = *(const float2*)(wcA + uy * 6 + 2);
                const float2 a2v = *(const float2*)(wcA + uy * 6 + 4);
                mA = fmaxf(mA, fmaxf(fmaxf(x0.x + a0.x, x0.y + a0.y),
                           fmaxf(fmaxf(x1.x + a1v.x, x1.y + a1v.y),
                                 fmaxf(x2.x + a2v.x, x2.y + a2v.y))));
                const float2 b0 = *(const float2*)(wcB + uy * 6);
                const float2 b1v = *(const float2*)(wcB + uy * 6 + 2);
                const float2 b2v = *(const float2*)(wcB + uy * 6 + 4);
                mB = fmaxf(mB, fmaxf(fmaxf(x0.x + b0.x, x0.y + b0.y),
                           fmaxf(fmaxf(x1.x + b1v.x, x1.y + b1v.y),
                                 fmaxf(x2.x + b2v.x, x2.y + b2v.y))));
            }
        }
        s_a2[ocl * 25 + pix] = fmaxf(mA - 1.0f, 0.0f);
        s_a2[(ocl + 8) * 25 + pix] = fmaxf(mB - 1.0f, 0.0f);
    }
    __syncthreads();

    // ---- L3 [16,5,5] -> [120]; 2 threads/output, 50 float4 each
    if (tid < 240) {
        const int o = tid >> 1, h = tid & 1;
        const float4* wv = (const float4*)(w3 + o * 400 + h * 200);
        const float4* av = (const float4*)(s_a2 + h * 200);
        float m = -1e30f;
        #pragma unroll 5
        for (int l = 0; l < 50; ++l) {
            const float4 w = wv[l];
            const float4 a = av[l];
            m = fmaxf(m, fmaxf(fmaxf(a.x + w.x, a.y + w.y),
                               fmaxf(a.z + w.z, a.w + w.w)));
        }
        m = fmaxf(m, __shfl_xor(m, 1));
        if (h == 0) s_a3[o] = fmaxf(m - 1.0f, 0.0f);
    }
    __syncthreads();

    // ---- Dense [120]->[84] + tanh; 2 threads/output
    if (tid < 168) {
        const int o = tid >> 1, h = tid & 1;
        float acc = 0.0f;
        #pragma unroll 4
        for (int i = 0; i < 60; ++i) {
            const int k = h * 60 + i;
            acc = fmaf(s_a3[k], wd[k * 84 + o], acc);
        }
        acc += __shfl_xor(acc, 1);
        if (h == 0) s_a4[o] = tanhf(acc);
    }
    __syncthreads();

    // ---- FC [84]->[10] + bias
    if (tid < 10) {
        float acc = bfv[tid];
        for (int i = 0; i < 84; ++i)
            acc = fmaf(s_a4[i], wf[i * 10 + tid], acc);
        s_logits[tid] = acc;
    }
    __syncthreads();

    // ---- log_softmax
    if (tid == 0) {
        float m = s_logits[0];
        for (int i = 1; i < 10; ++i) m = fmaxf(m, s_logits[i]);
        float s = 0.0f;
        for (int i = 0; i < 10; ++i) s += expf(s_logits[i] - m);
        s_red[0] = m;
        s_red[1] = logf(s);
    }
    __syncthreads();
    if (tid < 10)
        out[img * 10 + tid] = s_logits[tid] - s_red[0] - s_red[1];
}

extern "C" void kernel_launch(void* const* d_in, const int* in_sizes, int n_in,
                              void* d_out, int out_size, void* d_ws, size_t ws_size,
                              hipStream_t stream) {
    const float* x   = (const float*)d_in[0];
    const float* w1  = (const float*)d_in[1];
    const float* w2  = (const float*)d_in[2];
    const float* w3  = (const float*)d_in[3];
    const float* wd  = (const float*)d_in[4];
    const float* wf  = (const float*)d_in[5];
    const float* bfv = (const float*)d_in[6];
    float* out = (float*)d_out;

    const int B = in_sizes[0] / (3 * 32 * 32);
    float* a1 = (float*)d_ws;                                  // [B,6,14,14]
    unsigned* flags = (unsigned*)((char*)d_ws + (size_t)B * 1176 * 4); // [B,6]

    fused_lenet<<<dim3(B * 6), dim3(256), 0, stream>>>(
        x, w1, w2, w3, wd, wf, bfv, a1, flags, out);
}

// Round 6
// 84.680 us; speedup vs baseline: 1.5107x; 1.5107x over previous
//
#include <hip/hip_runtime.h>
#include <math.h>

// Fuzzy LeNet-5, Yager p=1 == Lukasiewicz: T(a,b)=max(0,a+b-1).
// Fuzzy conv == max-plus conv: out = relu(max_{c,kh,kw}(x+w) - 1).
// maxpool2 folds into the conv via dilated 6x6 weights:
//   W'[uy][ux] = max_{dy,dx in {0,1}, uy-dy,ux-dx in [0,5)} w[uy-dy][ux-dx]
//
// R5 post-mortem: cross-block producer/consumer handshake cost +26us (LLC
// round-trips, spinning consumers). Reverted. Single launch, one block per
// image, 512 threads. Key latency fixes vs the 41us R3 chain:
//  - channel-split partial tasks combined via LDS ds_max_u32 (relu>=0 floats
//    order as uints; relu(max-1)=max(relu(p-1)) is exact) -> conv1 is 504-way,
//    conv2 is 480-way parallel, no serial combine.
//  - conv2 loads each 14-float a1 row once per (c,uy) for 5 outputs (3x less
//    LDS traffic).
//  - head fully term-parallel; fc+log_softmax stay in one wave via shuffles.

#define NT 512
#define ROWS 34                 // padded image row stride
#define PLANE (32 * ROWS)       // 1088

__global__ __launch_bounds__(NT) void fused_lenet(
    const float* __restrict__ x,   // [B,3,32,32]
    const float* __restrict__ w1,  // [6,3,5,5]
    const float* __restrict__ w2,  // [16,6,5,5]
    const float* __restrict__ w3,  // [120,16,5,5]
    const float* __restrict__ wd,  // [120,84]
    const float* __restrict__ wf,  // [84,10]
    const float* __restrict__ bfv, // [10]
    float* __restrict__ out)       // [B,10]
{
    const int img = blockIdx.x;
    const int tid = threadIdx.x;

    __shared__ float s_in[3 * PLANE];          // 3264 f
    __shared__ float s_w1r[450];
    __shared__ float s_w2r[2400];
    __shared__ float s_w1d[648];               // [oc][c][uy][6]
    __shared__ float s_w2d[3456];              // [oc][c][uy][6]
    __shared__ unsigned s_a1u[1176];           // conv1 out, relu'd float bits
    __shared__ unsigned s_a2u[400];            // conv2 out, relu'd float bits
    __shared__ float s_a3[120];
    __shared__ float s_a4[84];

    // ---- Phase A: stage image (padded rows) + raw weights; zero accumulators
    {
        const float2* src = (const float2*)(x + img * 3072);
        for (int i = tid; i < 1536; i += NT) {
            const int c = i >> 9, rem = i & 511, r = rem >> 4, col2 = rem & 15;
            ((float2*)s_in)[c * (PLANE / 2) + r * (ROWS / 2) + col2] = src[i];
        }
        for (int i = tid; i < 225; i += NT)
            ((float2*)s_w1r)[i] = ((const float2*)w1)[i];
        for (int i = tid; i < 1200; i += NT)
            ((float2*)s_w2r)[i] = ((const float2*)w2)[i];
        for (int i = tid; i < 1176; i += NT) s_a1u[i] = 0u;
        if (tid < 400) s_a2u[tid] = 0u;
    }
    __syncthreads();

    // ---- Phase B: dilate both weight sets from LDS (648 + 3456 tasks)
    for (int e = tid; e < 4104; e += NT) {
        const float* raw;
        float* dst;
        int v;
        if (e < 648) {
            const int oc = e / 108, u = e - oc * 108;
            const int c = u / 36; v = u - c * 36;
            raw = s_w1r + (oc * 3 + c) * 25;
            dst = s_w1d + e;
        } else {
            const int idx = e - 648;
            const int oc = idx / 216, u = idx - oc * 216;
            const int c = u / 36; v = u - c * 36;
            raw = s_w2r + (oc * 6 + c) * 25;
            dst = s_w2d + idx;
        }
        const int r = v / 6, col = v - r * 6;
        float m = -1e30f;
        #pragma unroll
        for (int dy = 0; dy < 2; ++dy) {
            const int kh = r - dy;
            if ((unsigned)kh > 4u) continue;
            #pragma unroll
            for (int dx = 0; dx < 2; ++dx) {
                const int kw = col - dx;
                if ((unsigned)kw > 4u) continue;
                m = fmaxf(m, raw[kh * 5 + kw]);
            }
        }
        *dst = m;
    }
    __syncthreads();

    // ---- Phase C: conv1 partials, tasks (c,oc,py,s) = 504; 7-px strips
    if (tid < 504) {
        const int c = tid / 168;
        const int rr = tid - c * 168;
        const int oc = rr / 28;
        const int r2 = rr - oc * 28;
        const int py = r2 >> 1, s = r2 & 1;
        float acc[7];
        #pragma unroll
        for (int j = 0; j < 7; ++j) acc[j] = -1e30f;
        const float* wbase = s_w1d + (oc * 3 + c) * 36;
        #pragma unroll
        for (int uy = 0; uy < 6; ++uy) {
            const float* xr = s_in + c * PLANE + (2 * py + uy) * ROWS + 14 * s;
            float xv[18];
            #pragma unroll
            for (int i2 = 0; i2 < 9; ++i2)
                ((float2*)xv)[i2] = ((const float2*)xr)[i2];
            float wv[6];
            #pragma unroll
            for (int i2 = 0; i2 < 3; ++i2)
                ((float2*)wv)[i2] = ((const float2*)(wbase + uy * 6))[i2];
            #pragma unroll
            for (int j = 0; j < 7; ++j) {
                #pragma unroll
                for (int ux = 0; ux < 6; ++ux)
                    acc[j] = fmaxf(acc[j], xv[2 * j + ux] + wv[ux]);
            }
        }
        const int obase = oc * 196 + py * 14 + 7 * s;
        #pragma unroll
        for (int j = 0; j < 7; ++j) {
            const float rl = fmaxf(acc[j] - 1.0f, 0.0f);
            atomicMax(&s_a1u[obase + j], __float_as_uint(rl));
        }
    }
    __syncthreads();

    // ---- Phase D: conv2 partials, tasks (oc,py,c) = 480; 5-px rows
    if (tid < 480) {
        const int oc = tid / 30;
        const int rr = tid - oc * 30;
        const int py = rr / 6;
        const int c = rr - py * 6;
        float acc[5];
        #pragma unroll
        for (int j = 0; j < 5; ++j) acc[j] = -1e30f;
        const float* a1f = (const float*)s_a1u;
        const float* wbase = s_w2d + (oc * 6 + c) * 36;
        #pragma unroll
        for (int uy = 0; uy < 6; ++uy) {
            const float* xr = a1f + c * 196 + (2 * py + uy) * 14;
            float xv[14];
            #pragma unroll
            for (int i2 = 0; i2 < 7; ++i2)
                ((float2*)xv)[i2] = ((const float2*)xr)[i2];
            float wv[6];
            #pragma unroll
            for (int i2 = 0; i2 < 3; ++i2)
                ((float2*)wv)[i2] = ((const float2*)(wbase + uy * 6))[i2];
            #pragma unroll
            for (int j = 0; j < 5; ++j) {
                #pragma unroll
                for (int ux = 0; ux < 6; ++ux)
                    acc[j] = fmaxf(acc[j], xv[2 * j + ux] + wv[ux]);
            }
        }
        const int obase = oc * 25 + py * 5;
        #pragma unroll
        for (int j = 0; j < 5; ++j) {
            const float rl = fmaxf(acc[j] - 1.0f, 0.0f);
            atomicMax(&s_a2u[obase + j], __float_as_uint(rl));
        }
    }
    __syncthreads();

    // ---- Phase E: L3 [16,5,5]->[120]; 4 threads/output, 25 float4 each
    if (tid < 480) {
        const int o = tid >> 2, q = tid & 3;
        const float4* wv = (const float4*)(w3 + o * 400 + q * 100);
        const float4* av = (const float4*)((const float*)s_a2u + q * 100);
        float m = -1e30f;
        #pragma unroll 5
        for (int l = 0; l < 25; ++l) {
            const float4 w = wv[l];
            const float4 a = av[l];
            m = fmaxf(m, fmaxf(fmaxf(a.x + w.x, a.y + w.y),
                               fmaxf(a.z + w.z, a.w + w.w)));
        }
        m = fmaxf(m, __shfl_xor(m, 1));
        m = fmaxf(m, __shfl_xor(m, 2));
        if (q == 0) s_a3[o] = fmaxf(m - 1.0f, 0.0f);
    }
    __syncthreads();

    // ---- Phase F: dense [120]->[84] + tanh; 4 threads/output
    if (tid < 336) {
        const int o = tid >> 2, q = tid & 3;
        float acc = 0.0f;
        #pragma unroll 6
        for (int i = 0; i < 30; ++i) {
            const int k = q * 30 + i;
            acc = fmaf(s_a3[k], wd[k * 84 + o], acc);
        }
        acc += __shfl_xor(acc, 1);
        acc += __shfl_xor(acc, 2);
        if (q == 0) s_a4[o] = tanhf(acc);
    }
    __syncthreads();

    // ---- Phase G+H: fc [84]->[10] + bias + log_softmax, single wave
    if (tid < 64) {
        float acc = 0.0f;
        if (tid < 40) {
            const int o = tid >> 2, q = tid & 3;
            #pragma unroll 7
            for (int i = 0; i < 21; ++i) {
                const int k = q * 21 + i;
                acc = fmaf(s_a4[k], wf[k * 10 + o], acc);
            }
            acc += __shfl_xor(acc, 1);
            acc += __shfl_xor(acc, 2);
            acc += bfv[o];
        }
        // gather logits to lanes 0..9 (source lanes 0,4,...,36 all valid)
        const float lg = __shfl(acc, (tid < 10) ? tid * 4 : 0);
        if (tid < 16) {
            float v = (tid < 10) ? lg : -1e30f;
            #pragma unroll
            for (int d = 1; d < 16; d <<= 1)
                v = fmaxf(v, __shfl_xor(v, d));
            float e = (tid < 10) ? expf(lg - v) : 0.0f;
            float ssum = e;
            #pragma unroll
            for (int d = 1; d < 16; d <<= 1)
                ssum += __shfl_xor(ssum, d);
            if (tid < 10)
                out[img * 10 + tid] = lg - v - logf(ssum);
        }
    }
}

extern "C" void kernel_launch(void* const* d_in, const int* in_sizes, int n_in,
                              void* d_out, int out_size, void* d_ws, size_t ws_size,
                              hipStream_t stream) {
    const float* x   = (const float*)d_in[0];
    const float* w1  = (const float*)d_in[1];
    const float* w2  = (const float*)d_in[2];
    const float* w3  = (const float*)d_in[3];
    const float* wd  = (const float*)d_in[4];
    const float* wf  = (const float*)d_in[5];
    const float* bfv = (const float*)d_in[6];
    float* out = (float*)d_out;

    const int B = in_sizes[0] / (3 * 32 * 32);
    fused_lenet<<<dim3(B), dim3(NT), 0, stream>>>(
        x, w1, w2, w3, wd, wf, bfv, out);
}

// Round 7
// 81.909 us; speedup vs baseline: 1.5618x; 1.0338x over previous
//
#include <hip/hip_runtime.h>
#include <math.h>

// Fuzzy LeNet-5, Yager p=1 == Lukasiewicz: T(a,b)=max(0,a+b-1).
// Fuzzy conv == max-plus conv: out = relu(max_{c,kh,kw}(x+w) - 1).
// maxpool2 folds into the conv via dilated 6x6 weights:
//   W'[uy][ux] = max_{dy,dx in {0,1}, uy-dy,ux-dx in [0,5)} w[uy-dy][ux-dx]
//
// R6 post-mortem: 512-thr block = 26us kernel (latency-bound, 2 waves/SIMD).
// R7: 1024 threads (4 waves/SIMD, max), conv tasks split by uy-half so chains
// halve (1008 / 960 parallel tasks), stage+dilate merged into one phase
// (weights dilated straight from L2-hot global), head at 8 threads/output.
// Channel-partials combined via LDS atomicMax on relu'd float bits (exact:
// relu>=0 floats order as uints; relu(max-1)=max(relu(p-1))).

#define NT 1024
#define ROWS 34                 // padded image row stride
#define PLANE (32 * ROWS)       // 1088

__global__ __launch_bounds__(NT) void fused_lenet(
    const float* __restrict__ x,   // [B,3,32,32]
    const float* __restrict__ w1,  // [6,3,5,5]
    const float* __restrict__ w2,  // [16,6,5,5]
    const float* __restrict__ w3,  // [120,16,5,5]
    const float* __restrict__ wd,  // [120,84]
    const float* __restrict__ wf,  // [84,10]
    const float* __restrict__ bfv, // [10]
    float* __restrict__ out)       // [B,10]
{
    const int img = blockIdx.x;
    const int tid = threadIdx.x;

    __shared__ float s_in[3 * PLANE];          // 13056 B
    __shared__ float s_w1d[648];               // [oc][c][uy][6]
    __shared__ float s_w2d[3456];              // [oc][c][uy][6]
    __shared__ unsigned s_a1u[1176];           // conv1 out, relu'd float bits
    __shared__ unsigned s_a2u[400];            // conv2 out, relu'd float bits
    __shared__ float s_a3[120];
    __shared__ float s_a4[84];

    // ---- Phase AB: stage image + zero accums + dilate weights from global
    {
        const float2* src = (const float2*)(x + img * 3072);
        for (int i = tid; i < 1536; i += NT) {
            const int c = i >> 9, rem = i & 511, r = rem >> 4, col2 = rem & 15;
            ((float2*)s_in)[c * (PLANE / 2) + r * (ROWS / 2) + col2] = src[i];
        }
        for (int i = tid; i < 1176; i += NT) s_a1u[i] = 0u;
        if (tid < 400) s_a2u[tid] = 0u;

        for (int e = tid; e < 4104; e += NT) {
            const float* raw;
            float* dst;
            int v;
            if (e < 648) {
                const int oc = e / 108, u = e - oc * 108;
                const int c = u / 36; v = u - c * 36;
                raw = w1 + (oc * 3 + c) * 25;
                dst = s_w1d + e;
            } else {
                const int idx = e - 648;
                const int oc = idx / 216, u = idx - oc * 216;
                const int c = u / 36; v = u - c * 36;
                raw = w2 + (oc * 6 + c) * 25;
                dst = s_w2d + idx;
            }
            const int r = v / 6, col = v - r * 6;
            float m = -1e30f;
            #pragma unroll
            for (int dy = 0; dy < 2; ++dy) {
                const int kh = r - dy;
                if ((unsigned)kh > 4u) continue;
                #pragma unroll
                for (int dx = 0; dx < 2; ++dx) {
                    const int kw = col - dx;
                    if ((unsigned)kw > 4u) continue;
                    m = fmaxf(m, raw[kh * 5 + kw]);
                }
            }
            *dst = m;
        }
    }
    __syncthreads();

    // ---- Phase C: conv1 partials; 1008 tasks (c,oc,py,s,h), 3 uy x 7-px strip
    if (tid < 1008) {
        const int c = tid / 336;
        const int rr = tid - c * 336;
        const int oc = rr / 56;
        const int r2 = rr - oc * 56;
        const int py = r2 >> 2;
        const int s = (r2 >> 1) & 1;
        const int h = r2 & 1;
        float acc[7];
        #pragma unroll
        for (int j = 0; j < 7; ++j) acc[j] = -1e30f;
        const float* wbase = s_w1d + (oc * 3 + c) * 36 + h * 18;
        const float* xbase = s_in + c * PLANE + (2 * py + 3 * h) * ROWS + 14 * s;
        #pragma unroll
        for (int u = 0; u < 3; ++u) {
            const float* xr = xbase + u * ROWS;
            float xv[18];
            #pragma unroll
            for (int i2 = 0; i2 < 9; ++i2)
                ((float2*)xv)[i2] = ((const float2*)xr)[i2];
            float wv[6];
            #pragma unroll
            for (int i2 = 0; i2 < 3; ++i2)
                ((float2*)wv)[i2] = ((const float2*)(wbase + u * 6))[i2];
            #pragma unroll
            for (int j = 0; j < 7; ++j) {
                #pragma unroll
                for (int ux = 0; ux < 6; ++ux)
                    acc[j] = fmaxf(acc[j], xv[2 * j + ux] + wv[ux]);
            }
        }
        const int obase = oc * 196 + py * 14 + 7 * s;
        #pragma unroll
        for (int j = 0; j < 7; ++j) {
            const float rl = fmaxf(acc[j] - 1.0f, 0.0f);
            atomicMax(&s_a1u[obase + j], __float_as_uint(rl));
        }
    }
    __syncthreads();

    // ---- Phase D: conv2 partials; 960 tasks (oc,py,c,h), 3 uy x 5-px row
    if (tid < 960) {
        const int oc = tid / 60;
        const int rr = tid - oc * 60;
        const int py = rr / 12;
        const int r2 = rr - py * 12;
        const int c = r2 >> 1;
        const int h = r2 & 1;
        float acc[5];
        #pragma unroll
        for (int j = 0; j < 5; ++j) acc[j] = -1e30f;
        const float* a1f = (const float*)s_a1u;
        const float* wbase = s_w2d + (oc * 6 + c) * 36 + h * 18;
        const float* xbase = a1f + c * 196 + (2 * py + 3 * h) * 14;
        #pragma unroll
        for (int u = 0; u < 3; ++u) {
            const float* xr = xbase + u * 14;
            float xv[14];
            #pragma unroll
            for (int i2 = 0; i2 < 7; ++i2)
                ((float2*)xv)[i2] = ((const float2*)xr)[i2];
            float wv[6];
            #pragma unroll
            for (int i2 = 0; i2 < 3; ++i2)
                ((float2*)wv)[i2] = ((const float2*)(wbase + u * 6))[i2];
            #pragma unroll
            for (int j = 0; j < 5; ++j) {
                #pragma unroll
                for (int ux = 0; ux < 6; ++ux)
                    acc[j] = fmaxf(acc[j], xv[2 * j + ux] + wv[ux]);
            }
        }
        const int obase = oc * 25 + py * 5;
        #pragma unroll
        for (int j = 0; j < 5; ++j) {
            const float rl = fmaxf(acc[j] - 1.0f, 0.0f);
            atomicMax(&s_a2u[obase + j], __float_as_uint(rl));
        }
    }
    __syncthreads();

    // ---- Phase E: L3 [16,5,5]->[120]; 8 threads/output, 12-13 float4 each
    if (tid < 960) {
        const int o = tid >> 3, q = tid & 7;
        const float4* wv = (const float4*)(w3 + o * 400);
        const float4* av = (const float4*)(const float*)s_a2u;
        float m = -1e30f;
        for (int l = q; l < 100; l += 8) {
            const float4 w = wv[l];
            const float4 a = av[l];
            m = fmaxf(m, fmaxf(fmaxf(a.x + w.x, a.y + w.y),
                               fmaxf(a.z + w.z, a.w + w.w)));
        }
        m = fmaxf(m, __shfl_xor(m, 1));
        m = fmaxf(m, __shfl_xor(m, 2));
        m = fmaxf(m, __shfl_xor(m, 4));
        if (q == 0) s_a3[o] = fmaxf(m - 1.0f, 0.0f);
    }
    __syncthreads();

    // ---- Phase F: dense [120]->[84] + tanh; 8 threads/output, 15 terms each
    if (tid < 672) {
        const int o = tid >> 3, q = tid & 7;
        float acc = 0.0f;
        #pragma unroll 5
        for (int i = 0; i < 15; ++i) {
            const int k = q * 15 + i;
            acc = fmaf(s_a3[k], wd[k * 84 + o], acc);
        }
        acc += __shfl_xor(acc, 1);
        acc += __shfl_xor(acc, 2);
        acc += __shfl_xor(acc, 4);
        if (q == 0) s_a4[o] = tanhf(acc);
    }
    __syncthreads();

    // ---- Phase G: fc [84]->[10] + bias + log_softmax, single wave
    if (tid < 64) {
        float acc = 0.0f;
        if (tid < 40) {
            const int o = tid >> 2, q = tid & 3;
            #pragma unroll 7
            for (int i = 0; i < 21; ++i) {
                const int k = q * 21 + i;
                acc = fmaf(s_a4[k], wf[k * 10 + o], acc);
            }
            acc += __shfl_xor(acc, 1);
            acc += __shfl_xor(acc, 2);
            acc += bfv[o];
        }
        const float lg = __shfl(acc, (tid < 10) ? tid * 4 : 0);
        if (tid < 16) {
            float v = (tid < 10) ? lg : -1e30f;
            #pragma unroll
            for (int d = 1; d < 16; d <<= 1)
                v = fmaxf(v, __shfl_xor(v, d));
            float e = (tid < 10) ? expf(lg - v) : 0.0f;
            float ssum = e;
            #pragma unroll
            for (int d = 1; d < 16; d <<= 1)
                ssum += __shfl_xor(ssum, d);
            if (tid < 10)
                out[img * 10 + tid] = lg - v - logf(ssum);
        }
    }
}

extern "C" void kernel_launch(void* const* d_in, const int* in_sizes, int n_in,
                              void* d_out, int out_size, void* d_ws, size_t ws_size,
                              hipStream_t stream) {
    const float* x   = (const float*)d_in[0];
    const float* w1  = (const float*)d_in[1];
    const float* w2  = (const float*)d_in[2];
    const float* w3  = (const float*)d_in[3];
    const float* wd  = (const float*)d_in[4];
    const float* wf  = (const float*)d_in[5];
    const float* bfv = (const float*)d_in[6];
    float* out = (float*)d_out;

    const int B = in_sizes[0] / (3 * 32 * 32);
    fused_lenet<<<dim3(B), dim3(NT), 0, stream>>>(
        x, w1, w2, w3, wd, wf, bfv, out);
}

// Round 8
// 78.101 us; speedup vs baseline: 1.6380x; 1.0488x over previous
//
#include <hip/hip_runtime.h>
#include <math.h>

// Fuzzy LeNet-5, Yager p=1 == Lukasiewicz: T(a,b)=max(0,a+b-1).
// Fuzzy conv == max-plus conv: out = relu(max_{c,kh,kw}(x+w) - 1).
// maxpool2 folds into the conv via dilated 6x6 weights:
//   W'[uy][ux] = max_{dy,dx in {0,1}, uy-dy,ux-dx in [0,5)} w[uy-dy][ux-dx]
//
// R7 post-mortem: 23.5us kernel; barrier-separated phases expose L2 latency
// (w3: 192KB/block read in phase E). R8: register software-prefetch --
// w3 fragments (13 float4/thread) issued at kernel entry, consumed in E;
// w2 dilation moved after conv1 body (overlaps conv1 compute);
// wd (15 f/thread) issued before conv2's barrier, consumed in F.
// Index clamp-to-99 in the w3 prefetch avoids predication: duplicate terms
// are exact under max (all l in [0,400) belong to the same output's max).
// Channel-partials combined via LDS atomicMax on relu'd float bits (exact).

#define NT 1024
#define ROWS 34                 // padded image row stride
#define PLANE (32 * ROWS)       // 1088

__global__ __launch_bounds__(NT) void fused_lenet(
    const float* __restrict__ x,   // [B,3,32,32]
    const float* __restrict__ w1,  // [6,3,5,5]
    const float* __restrict__ w2,  // [16,6,5,5]
    const float* __restrict__ w3,  // [120,16,5,5]
    const float* __restrict__ wd,  // [120,84]
    const float* __restrict__ wf,  // [84,10]
    const float* __restrict__ bfv, // [10]
    float* __restrict__ out)       // [B,10]
{
    const int img = blockIdx.x;
    const int tid = threadIdx.x;

    __shared__ float s_in[3 * PLANE];          // 13056 B
    __shared__ float s_w1d[648];               // [oc][c][uy][6]
    __shared__ float s_w2d[3456];              // [oc][c][uy][6]
    __shared__ unsigned s_a1u[1176];           // conv1 out, relu'd float bits
    __shared__ unsigned s_a2u[400];            // conv2 out, relu'd float bits
    __shared__ float s_a3[120];
    __shared__ float s_a4[84];

    // ---- Prefetch w3 fragments into registers (in flight through A..D)
    float4 w3p[13];
    if (tid < 960) {
        const int o = tid >> 3, q = tid & 7;
        const float4* wv = (const float4*)(w3 + o * 400);
        #pragma unroll
        for (int i = 0; i < 13; ++i) {
            int l = q + 8 * i; if (l > 99) l = 99;
            w3p[i] = wv[l];
        }
    }

    // ---- Phase A: stage image + zero accums + dilate w1
    {
        const float2* src = (const float2*)(x + img * 3072);
        for (int i = tid; i < 1536; i += NT) {
            const int c = i >> 9, rem = i & 511, r = rem >> 4, col2 = rem & 15;
            ((float2*)s_in)[c * (PLANE / 2) + r * (ROWS / 2) + col2] = src[i];
        }
        for (int i = tid; i < 1176; i += NT) s_a1u[i] = 0u;
        if (tid < 400) s_a2u[tid] = 0u;
        if (tid < 648) {
            const int oc = tid / 108, u = tid - oc * 108;
            const int c = u / 36, v = u - c * 36;
            const int r = v / 6, col = v - r * 6;
            const float* raw = w1 + (oc * 3 + c) * 25;
            float m = -1e30f;
            #pragma unroll
            for (int dy = 0; dy < 2; ++dy) {
                const int kh = r - dy;
                if ((unsigned)kh > 4u) continue;
                #pragma unroll
                for (int dx = 0; dx < 2; ++dx) {
                    const int kw = col - dx;
                    if ((unsigned)kw > 4u) continue;
                    m = fmaxf(m, raw[kh * 5 + kw]);
                }
            }
            s_w1d[tid] = m;
        }
    }
    __syncthreads();

    // ---- Phase C: conv1 partials; 1008 tasks (c,oc,py,s,h), 3 uy x 7-px strip
    if (tid < 1008) {
        const int c = tid / 336;
        const int rr = tid - c * 336;
        const int oc = rr / 56;
        const int r2 = rr - oc * 56;
        const int py = r2 >> 2;
        const int s = (r2 >> 1) & 1;
        const int h = r2 & 1;
        float acc[7];
        #pragma unroll
        for (int j = 0; j < 7; ++j) acc[j] = -1e30f;
        const float* wbase = s_w1d + (oc * 3 + c) * 36 + h * 18;
        const float* xbase = s_in + c * PLANE + (2 * py + 3 * h) * ROWS + 14 * s;
        #pragma unroll
        for (int u = 0; u < 3; ++u) {
            const float* xr = xbase + u * ROWS;
            float xv[18];
            #pragma unroll
            for (int i2 = 0; i2 < 9; ++i2)
                ((float2*)xv)[i2] = ((const float2*)xr)[i2];
            float wv[6];
            #pragma unroll
            for (int i2 = 0; i2 < 3; ++i2)
                ((float2*)wv)[i2] = ((const float2*)(wbase + u * 6))[i2];
            #pragma unroll
            for (int j = 0; j < 7; ++j) {
                #pragma unroll
                for (int ux = 0; ux < 6; ++ux)
                    acc[j] = fmaxf(acc[j], xv[2 * j + ux] + wv[ux]);
            }
        }
        const int obase = oc * 196 + py * 14 + 7 * s;
        #pragma unroll
        for (int j = 0; j < 7; ++j) {
            const float rl = fmaxf(acc[j] - 1.0f, 0.0f);
            atomicMax(&s_a1u[obase + j], __float_as_uint(rl));
        }
    }
    // dilate w2 from global (overlaps conv1 across waves; same barrier covers)
    for (int e = tid; e < 3456; e += NT) {
        const int oc = e / 216, u = e - oc * 216;
        const int c = u / 36, v = u - c * 36;
        const int r = v / 6, col = v - r * 6;
        const float* raw = w2 + (oc * 6 + c) * 25;
        float m = -1e30f;
        #pragma unroll
        for (int dy = 0; dy < 2; ++dy) {
            const int kh = r - dy;
            if ((unsigned)kh > 4u) continue;
            #pragma unroll
            for (int dx = 0; dx < 2; ++dx) {
                const int kw = col - dx;
                if ((unsigned)kw > 4u) continue;
                m = fmaxf(m, raw[kh * 5 + kw]);
            }
        }
        s_w2d[e] = m;
    }
    __syncthreads();

    // ---- Phase D: conv2 partials; 960 tasks (oc,py,c,h), 3 uy x 5-px row
    if (tid < 960) {
        const int oc = tid / 60;
        const int rr = tid - oc * 60;
        const int py = rr / 12;
        const int r2 = rr - py * 12;
        const int c = r2 >> 1;
        const int h = r2 & 1;
        float acc[5];
        #pragma unroll
        for (int j = 0; j < 5; ++j) acc[j] = -1e30f;
        const float* a1f = (const float*)s_a1u;
        const float* wbase = s_w2d + (oc * 6 + c) * 36 + h * 18;
        const float* xbase = a1f + c * 196 + (2 * py + 3 * h) * 14;
        #pragma unroll
        for (int u = 0; u < 3; ++u) {
            const float* xr = xbase + u * 14;
            float xv[14];
            #pragma unroll
            for (int i2 = 0; i2 < 7; ++i2)
                ((float2*)xv)[i2] = ((const float2*)xr)[i2];
            float wv[6];
            #pragma unroll
            for (int i2 = 0; i2 < 3; ++i2)
                ((float2*)wv)[i2] = ((const float2*)(wbase + u * 6))[i2];
            #pragma unroll
            for (int j = 0; j < 5; ++j) {
                #pragma unroll
                for (int ux = 0; ux < 6; ++ux)
                    acc[j] = fmaxf(acc[j], xv[2 * j + ux] + wv[ux]);
            }
        }
        const int obase = oc * 25 + py * 5;
        #pragma unroll
        for (int j = 0; j < 5; ++j) {
            const float rl = fmaxf(acc[j] - 1.0f, 0.0f);
            atomicMax(&s_a2u[obase + j], __float_as_uint(rl));
        }
    }
    // prefetch wd for the dense phase (in flight during E)
    float wdp[15];
    if (tid < 672) {
        const int o = tid >> 3, q = tid & 7;
        #pragma unroll
        for (int i = 0; i < 15; ++i)
            wdp[i] = wd[(q * 15 + i) * 84 + o];
    }
    __syncthreads();

    // ---- Phase E: L3 [16,5,5]->[120]; 8 threads/output, prefetched w3
    if (tid < 960) {
        const int o = tid >> 3, q = tid & 7;
        const float4* av = (const float4*)(const float*)s_a2u;
        float m = -1e30f;
        #pragma unroll
        for (int i = 0; i < 13; ++i) {
            int l = q + 8 * i; if (l > 99) l = 99;
            const float4 a = av[l];
            const float4 w = w3p[i];
            m = fmaxf(m, fmaxf(fmaxf(a.x + w.x, a.y + w.y),
                               fmaxf(a.z + w.z, a.w + w.w)));
        }
        m = fmaxf(m, __shfl_xor(m, 1));
        m = fmaxf(m, __shfl_xor(m, 2));
        m = fmaxf(m, __shfl_xor(m, 4));
        if (q == 0) s_a3[o] = fmaxf(m - 1.0f, 0.0f);
    }
    __syncthreads();

    // ---- Phase F: dense [120]->[84] + tanh; 8 threads/output, prefetched wd
    if (tid < 672) {
        const int o = tid >> 3, q = tid & 7;
        float acc = 0.0f;
        #pragma unroll
        for (int i = 0; i < 15; ++i)
            acc = fmaf(s_a3[q * 15 + i], wdp[i], acc);
        acc += __shfl_xor(acc, 1);
        acc += __shfl_xor(acc, 2);
        acc += __shfl_xor(acc, 4);
        if (q == 0) s_a4[o] = tanhf(acc);
    }
    __syncthreads();

    // ---- Phase G: fc [84]->[10] + bias + log_softmax, single wave
    if (tid < 64) {
        float acc = 0.0f;
        if (tid < 40) {
            const int o = tid >> 2, q = tid & 3;
            #pragma unroll 7
            for (int i = 0; i < 21; ++i) {
                const int k = q * 21 + i;
                acc = fmaf(s_a4[k], wf[k * 10 + o], acc);
            }
            acc += __shfl_xor(acc, 1);
            acc += __shfl_xor(acc, 2);
            acc += bfv[o];
        }
        const float lg = __shfl(acc, (tid < 10) ? tid * 4 : 0);
        if (tid < 16) {
            float v = (tid < 10) ? lg : -1e30f;
            #pragma unroll
            for (int d = 1; d < 16; d <<= 1)
                v = fmaxf(v, __shfl_xor(v, d));
            float e = (tid < 10) ? expf(lg - v) : 0.0f;
            float ssum = e;
            #pragma unroll
            for (int d = 1; d < 16; d <<= 1)
                ssum += __shfl_xor(ssum, d);
            if (tid < 10)
                out[img * 10 + tid] = lg - v - logf(ssum);
        }
    }
}

extern "C" void kernel_launch(void* const* d_in, const int* in_sizes, int n_in,
                              void* d_out, int out_size, void* d_ws, size_t ws_size,
                              hipStream_t stream) {
    const float* x   = (const float*)d_in[0];
    const float* w1  = (const float*)d_in[1];
    const float* w2  = (const float*)d_in[2];
    const float* w3  = (const float*)d_in[3];
    const float* wd  = (const float*)d_in[4];
    const float* wf  = (const float*)d_in[5];
    const float* bfv = (const float*)d_in[6];
    float* out = (float*)d_out;

    const int B = in_sizes[0] / (3 * 32 * 32);
    fused_lenet<<<dim3(B), dim3(NT), 0, stream>>>(
        x, w1, w2, w3, wd, wf, bfv, out);
}